// Round 6
// baseline (248.290 us; speedup 1.0000x reference)
//
#include <hip/hip_runtime.h>

#define NHEADS 12
#define HDIM   64
#define EMB    768
#define SEQ    1024
#define BATCH  4
#define MTOT   (BATCH * SEQ)

typedef __bf16 bf16x8 __attribute__((ext_vector_type(8)));
typedef float  f32x4  __attribute__((ext_vector_type(4)));
typedef float  f32x16 __attribute__((ext_vector_type(16)));

#define GLB(p) ((const __attribute__((address_space(1))) uint32_t*)(p))
#define LDS(p) ((__attribute__((address_space(3))) uint32_t*)(p))

__device__ __forceinline__ uint bfr(float f) {  // f32 -> bf16 bits, RNE
    uint u = __float_as_uint(f);
    return (u + 0x7fffu + ((u >> 16) & 1u)) >> 16;
}

// ---------------------------------------------------------------------------
// One launch: split hs (3072 blocks) + 4 weights (576 blocks each) to hi/lo.
// ---------------------------------------------------------------------------
__global__ __launch_bounds__(256) void split_all(
    const float* __restrict__ hs,
    const float* __restrict__ w0, const float* __restrict__ w1,
    const float* __restrict__ w2, const float* __restrict__ w3,
    ushort* __restrict__ hsh, ushort* __restrict__ hsl,
    ushort* __restrict__ wch, ushort* __restrict__ wcl,
    ushort* __restrict__ woh, ushort* __restrict__ wol)
{
    const int bx = blockIdx.x;
    const float* src;
    ushort *hi, *lo;
    int i;
    if (bx < 3072) {
        src = hs; hi = hsh; lo = hsl;
        i = bx * 256 + threadIdx.x;
    } else {
        const int y = (bx - 3072) / 576;
        const int r = (bx - 3072) - y * 576;
        src = (y == 0) ? w0 : (y == 1) ? w1 : (y == 2) ? w2 : w3;
        hi = (y < 3) ? (wch + (size_t)y * (EMB * EMB)) : woh;
        lo = (y < 3) ? (wcl + (size_t)y * (EMB * EMB)) : wol;
        i = r * 256 + threadIdx.x;
    }
    float4 v = ((const float4*)src)[i];
    float f[4] = {v.x, v.y, v.z, v.w};
    ushort hh[4], ll[4];
#pragma unroll
    for (int j = 0; j < 4; ++j) {
        uint h = bfr(f[j]);
        float hf = __uint_as_float(h << 16);
        ll[j] = (ushort)bfr(f[j] - hf);
        hh[j] = (ushort)h;
    }
    ushort4 hv = {hh[0], hh[1], hh[2], hh[3]};
    ushort4 lv = {ll[0], ll[1], ll[2], ll[3]};
    ((ushort4*)hi)[i] = hv;
    ((ushort4*)lo)[i] = lv;
}

// ---------------------------------------------------------------------------
// QKV GEMM: 128x128 tile, 4 waves x (64x64 each) via mfma_f32_32x32x16_bf16,
// BK=16, QUAD-buffered LDS (barrier per 2 K-steps -> vmcnt drain covers loads
// issued ~2 compute-steps earlier). LDS subtile layout [slot(2)][row][16B]
// gives conflict-free ds_read_b128 with linear global_load_lds staging.
// bf16 hi/lo 3-MFMA products. q,k -> [B,H,S,D] bf16; v -> [B,H,D,S] bf16.
// ---------------------------------------------------------------------------
__global__ __launch_bounds__(256, 2) void gemm_qkv(
    const ushort* __restrict__ Ah, const ushort* __restrict__ Al,
    const ushort* __restrict__ Wh, const ushort* __restrict__ Wl,
    const float* __restrict__ b0, const float* __restrict__ b1,
    const float* __restrict__ b2,
    ushort* __restrict__ q16, ushort* __restrict__ k16,
    ushort* __restrict__ vT16)
{
    // 4 buffers x 16KB; buffer = [Ah 4K][Al 4K][Bh 4K][Bl 4K]
    __shared__ __align__(16) char lds[65536];

    const int t = threadIdx.x;
    const int w = t >> 6, l = t & 63;
    const int m0 = blockIdx.x * 128;
    const int n0 = blockIdx.y * 128;
    const int wm = w >> 1, wn = w & 1;

    const char* gA[2] = {(const char*)Ah + (size_t)m0 * 1536,
                         (const char*)Al + (size_t)m0 * 1536};
    const char* gW[2] = {(const char*)Wh + (size_t)n0 * 1536,
                         (const char*)Wl + (size_t)n0 * 1536};

    // staging: thread t covers dest offset t*16 of each 4KB subtile:
    // slot = t>>7, row = t&127 ; global = row*1536 + ks*32 + slot*16
    const size_t gsb = (size_t)(t & 127) * 1536 + (t >> 7) * 16;
    const int ldsu = w * 1024;  // wave-uniform part of dest (lane*16 implicit)

    // frag read offsets: [slot][row][16B]
    int aoff[2], boff[2];
#pragma unroll
    for (int i = 0; i < 2; ++i)
        aoff[i] = (l >> 5) * 2048 + (wm * 64 + i * 32 + (l & 31)) * 16;
#pragma unroll
    for (int j = 0; j < 2; ++j)
        boff[j] = (l >> 5) * 2048 + (wn * 64 + j * 32 + (l & 31)) * 16;

    f32x16 acc[2][2] = {};

    auto stage = [&](int ks) {
        char* dst = lds + (ks & 3) * 16384;
        const size_t go = gsb + (size_t)ks * 32;
        __builtin_amdgcn_global_load_lds(GLB(gA[0] + go), LDS(dst + ldsu), 16, 0, 0);
        __builtin_amdgcn_global_load_lds(GLB(gA[1] + go), LDS(dst + 4096 + ldsu), 16, 0, 0);
        __builtin_amdgcn_global_load_lds(GLB(gW[0] + go), LDS(dst + 8192 + ldsu), 16, 0, 0);
        __builtin_amdgcn_global_load_lds(GLB(gW[1] + go), LDS(dst + 12288 + ldsu), 16, 0, 0);
    };

    auto compute = [&](int ks) {
        const char* cur = lds + (ks & 3) * 16384;
        bf16x8 ah[2], al[2], bh[2], bl[2];
#pragma unroll
        for (int i = 0; i < 2; ++i) {
            ah[i] = *(const bf16x8*)(cur + aoff[i]);
            al[i] = *(const bf16x8*)(cur + 4096 + aoff[i]);
        }
#pragma unroll
        for (int j = 0; j < 2; ++j) {
            bh[j] = *(const bf16x8*)(cur + 8192 + boff[j]);
            bl[j] = *(const bf16x8*)(cur + 12288 + boff[j]);
        }
        __builtin_amdgcn_s_setprio(1);
#pragma unroll
        for (int i = 0; i < 2; ++i)
#pragma unroll
            for (int j = 0; j < 2; ++j) {
                acc[i][j] = __builtin_amdgcn_mfma_f32_32x32x16_bf16(ah[i], bh[j], acc[i][j], 0, 0, 0);
                acc[i][j] = __builtin_amdgcn_mfma_f32_32x32x16_bf16(ah[i], bl[j], acc[i][j], 0, 0, 0);
                acc[i][j] = __builtin_amdgcn_mfma_f32_32x32x16_bf16(al[i], bh[j], acc[i][j], 0, 0, 0);
            }
        __builtin_amdgcn_s_setprio(0);
    };

    stage(0);
    stage(1);
    __syncthreads();

    for (int kb = 0; kb < 48; kb += 2) {
        if (kb + 2 < 48) stage(kb + 2);
        if (kb + 3 < 48) stage(kb + 3);
        compute(kb);
        compute(kb + 1);
        __syncthreads();
    }

    // ---- epilogue: C layout col=lane&31, row=(r&3)+8*(r>>2)+4*(lane>>5) ----
    const int lrow = 4 * (l >> 5);
    const int lcol = l & 31;
    const int which = (n0 >= 1536) ? 2 : (n0 >= 768 ? 1 : 0);
    const int nb = n0 - which * 768 + wn * 64;

    if (which == 2) {
#pragma unroll
        for (int j = 0; j < 2; ++j) {
            const int n_in = nb + j * 32 + lcol;
            const float bv = b2[n_in];
            const int h = n_in >> 6, d = n_in & 63;
#pragma unroll
            for (int i = 0; i < 2; ++i) {
                const int m_base = m0 + wm * 64 + i * 32 + lrow;
                const int bb = m_base >> 10, s_base = m_base & 1023;
                ushort* bp = vT16 + ((size_t)(bb * NHEADS + h) * HDIM + d) * SEQ + s_base;
#pragma unroll
                for (int g = 0; g < 4; ++g) {
                    ushort4 pk = {(ushort)bfr(acc[i][j][4 * g + 0] + bv),
                                  (ushort)bfr(acc[i][j][4 * g + 1] + bv),
                                  (ushort)bfr(acc[i][j][4 * g + 2] + bv),
                                  (ushort)bfr(acc[i][j][4 * g + 3] + bv)};
                    *(ushort4*)(bp + 8 * g) = pk;
                }
            }
        }
    } else {
        ushort* op = (which == 0) ? q16 : k16;
        const float* bpt = (which == 0) ? b0 : b1;
        const float scale = (which == 0) ? 0.125f : 1.0f;
#pragma unroll
        for (int j = 0; j < 2; ++j) {
            const int n_in = nb + j * 32 + lcol;
            const float bv = bpt[n_in];
            const int h = n_in >> 6, d = n_in & 63;
#pragma unroll
            for (int i = 0; i < 2; ++i) {
                const int m_base = m0 + wm * 64 + i * 32 + lrow;
#pragma unroll
                for (int r = 0; r < 16; ++r) {
                    const int m = m_base + (r & 3) + 8 * (r >> 2);
                    const int bb = m >> 10, s = m & 1023;
                    op[(size_t)((bb * NHEADS + h) * SEQ + s) * HDIM + d] =
                        (ushort)bfr((acc[i][j][r] + bv) * scale);
                }
            }
        }
    }
}

// ---------------------------------------------------------------------------
// o-projection GEMM (round-5 structure, renamed for profiling visibility):
// BM=64 x 128, 512 thr = 8 waves of 32x32, 16x16x32 MFMA, double-buffered.
// ---------------------------------------------------------------------------
__global__ __launch_bounds__(512) void gemm_oproj(
    const ushort* __restrict__ Ah, const ushort* __restrict__ Al,
    const ushort* __restrict__ Wh, const ushort* __restrict__ Wl,
    const float* __restrict__ b0, float* __restrict__ o0)
{
    constexpr int SA = 64 * 64;          // 4096
    constexpr int SB = 8192;
    constexpr int TS = 2 * SA + 2 * SB;  // 24576

    __shared__ __align__(16) char ldsc[2 * TS];

    const int t  = threadIdx.x;
    const int w  = t >> 6;
    const int l  = t & 63;
    const int m0 = blockIdx.x * 64;
    const int n0 = blockIdx.y * 128;
    const int wm = w >> 2;
    const int wn = w & 3;

    const char* gb[4] = {
        (const char*)Ah + (size_t)m0 * 1536,
        (const char*)Al + (size_t)m0 * 1536,
        (const char*)Wh + (size_t)n0 * 1536,
        (const char*)Wl + (size_t)n0 * 1536};

    int aoff[2], boff[2];
#pragma unroll
    for (int i = 0; i < 2; ++i) {
        int row = wm * 32 + i * 16 + (l & 15);
        aoff[i] = row * 64 + ((((l >> 4) ^ ((row >> 1) & 3))) << 4);
    }
#pragma unroll
    for (int i = 0; i < 2; ++i) {
        int rn = wn * 32 + i * 16 + (l & 15);
        boff[i] = rn * 64 + ((((l >> 4) ^ ((rn >> 1) & 3))) << 4);
    }

    auto stage = [&](int ks, int buf) {
        const size_t kb = (size_t)ks * 64;
        char* dst = ldsc + buf * TS;
#pragma unroll
        for (int tt = 0; tt < 4; ++tt) {
            const int tsz  = (tt < 2) ? SA : SB;
            const int tbas = (tt == 0) ? 0 : (tt == 1) ? SA
                           : (tt == 2) ? 2 * SA : 2 * SA + SB;
#pragma unroll
            for (int p = 0; p < tsz; p += 8192) {
                const int soff = p + t * 16;
                if (soff < tsz) {
                    const int srow = soff >> 6;
                    const int slot = (soff >> 4) & 3;
                    const size_t go = (size_t)srow * 1536 +
                                      ((slot ^ ((srow >> 1) & 3)) << 4) + kb;
                    __builtin_amdgcn_global_load_lds(GLB(gb[tt] + go),
                                                     LDS(dst + tbas + soff), 16, 0, 0);
                }
            }
        }
    };

    f32x4 acc[2][2] = {};

    stage(0, 0);
    __syncthreads();

    for (int ks = 0; ks < 24; ++ks) {
        if (ks + 1 < 24) stage(ks + 1, (ks + 1) & 1);

        const char* cur = ldsc + (ks & 1) * TS;
        bf16x8 ah[2], al[2], bh[2], bl[2];
#pragma unroll
        for (int i = 0; i < 2; ++i) {
            ah[i] = *(const bf16x8*)(cur + aoff[i]);
            al[i] = *(const bf16x8*)(cur + SA + aoff[i]);
        }
#pragma unroll
        for (int i = 0; i < 2; ++i) {
            bh[i] = *(const bf16x8*)(cur + 2 * SA + boff[i]);
            bl[i] = *(const bf16x8*)(cur + 2 * SA + SB + boff[i]);
        }
#pragma unroll
        for (int i = 0; i < 2; ++i)
#pragma unroll
            for (int j = 0; j < 2; ++j) {
                acc[i][j] = __builtin_amdgcn_mfma_f32_16x16x32_bf16(ah[i], bh[j], acc[i][j], 0, 0, 0);
                acc[i][j] = __builtin_amdgcn_mfma_f32_16x16x32_bf16(ah[i], bl[j], acc[i][j], 0, 0, 0);
                acc[i][j] = __builtin_amdgcn_mfma_f32_16x16x32_bf16(al[i], bh[j], acc[i][j], 0, 0, 0);
            }
        __syncthreads();
    }

    const int mrow_base = m0 + wm * 32 + ((l >> 4) << 2);
    const int nin_base = n0 + wn * 32 + (l & 15);
#pragma unroll
    for (int j = 0; j < 2; ++j) {
        const int n_in = nin_base + j * 16;
        const float bv = b0[n_in];
#pragma unroll
        for (int i = 0; i < 2; ++i)
#pragma unroll
            for (int r = 0; r < 4; ++r) {
                const int m = mrow_base + i * 16 + r;
                o0[(size_t)m * 768 + n_in] = acc[i][j][r] + bv;
            }
    }
}

// ---------------------------------------------------------------------------
// Flash attention, bf16 MFMA, double-buffered K/V (unchanged).
// ---------------------------------------------------------------------------
#define QPOFF  0
#define KOFF   8192
#define VOFF   24576
#define POSOFF 40960

__global__ __launch_bounds__(256) void attn_mfma(
    const ushort* __restrict__ q16, const ushort* __restrict__ k16,
    const ushort* __restrict__ vT16, const int* __restrict__ pos_row,
    const int* __restrict__ pos_col, const float* __restrict__ rel_table,
    ushort* __restrict__ aoh, ushort* __restrict__ aol)
{
    __shared__ __align__(16) char lds[41472];

    const int t  = threadIdx.x;
    const int w  = t >> 6;
    const int l  = t & 63;
    const int bh = blockIdx.y;
    const int b  = bh / NHEADS;
    const int h  = bh - b * NHEADS;
    const int q0g = blockIdx.x * 64;

    const char* qb  = (const char*)(q16 + (size_t)bh * SEQ * HDIM);
    const char* kb  = (const char*)(k16 + (size_t)bh * SEQ * HDIM);
    const char* vtb = (const char*)(vT16 + (size_t)bh * HDIM * SEQ);

    const float t0 = rel_table[0 * NHEADS + h];
    const float t1 = rel_table[1 * NHEADS + h];
    const float t2 = rel_table[2 * NHEADS + h];
    const float t3 = rel_table[3 * NHEADS + h];

    const int o1 = t * 16, o2 = o1 + 4096;
    const int r1 = o1 >> 7, r2 = o2 >> 7;
    const int kq1 = o1 ^ ((r1 & 7) << 4);
    const int kq2 = o2 ^ ((r2 & 7) << 4);
    const int vs1 = r1 * 2048 + (((((o1 >> 4) & 7) ^ (r1 & 7))) << 4);
    const int vs2 = r2 * 2048 + (((((o2 >> 4) & 7) ^ (r2 & 7))) << 4);

    auto stage_kv = [&](int kt, int buf) {
        const int k0g = kt * 64;
        __builtin_amdgcn_global_load_lds(GLB(kb + (size_t)k0g * 128 + kq1),
                                         LDS(lds + KOFF + buf * 8192 + w * 1024), 16, 0, 0);
        __builtin_amdgcn_global_load_lds(GLB(kb + (size_t)k0g * 128 + kq2),
                                         LDS(lds + KOFF + buf * 8192 + w * 1024 + 4096), 16, 0, 0);
        __builtin_amdgcn_global_load_lds(GLB(vtb + (size_t)k0g * 2 + vs1),
                                         LDS(lds + VOFF + buf * 8192 + w * 1024), 16, 0, 0);
        __builtin_amdgcn_global_load_lds(GLB(vtb + (size_t)k0g * 2 + vs2),
                                         LDS(lds + VOFF + buf * 8192 + w * 1024 + 4096), 16, 0, 0);
        if (t < 64) {
            int pr = pos_row[b * SEQ + k0g + t];
            int pc = pos_col[b * SEQ + k0g + t];
            *(int*)(lds + POSOFF + buf * 256 + t * 4) = (pr << 8) | pc;
        }
    };

    __builtin_amdgcn_global_load_lds(GLB(qb + (size_t)q0g * 128 + kq1),
                                     LDS(lds + QPOFF + w * 1024), 16, 0, 0);
    __builtin_amdgcn_global_load_lds(GLB(qb + (size_t)q0g * 128 + kq2),
                                     LDS(lds + QPOFF + w * 1024 + 4096), 16, 0, 0);
    stage_kv(0, 0);

    const int qrow_g = q0g + w * 16 + (l & 15);
    const int pq = (pos_row[b * SEQ + qrow_g] << 8) | pos_col[b * SEQ + qrow_g];

    __syncthreads();

    bf16x8 qf[2];
    const int qrl = w * 16 + (l & 15);
#pragma unroll
    for (int ks = 0; ks < 2; ++ks)
        qf[ks] = *(const bf16x8*)(lds + QPOFF + qrl * 128 +
                                  ((((l >> 4) + 4 * ks) ^ (qrl & 7)) << 4));

    f32x4 pv[4] = {};
    float m_run = -1e30f, l_run = 0.0f;

    const int prow = l & 15;
    const int pswz = (prow & 7) << 4;
    const int pwbase = QPOFF + w * 2048 + prow * 128;

    for (int kt = 0; kt < 16; ++kt) {
        const int cb = kt & 1;
        if (kt + 1 < 16) stage_kv(kt + 1, cb ^ 1);
        const char* kbuf = lds + KOFF + cb * 8192;
        const char* vbuf = lds + VOFF + cb * 8192;
        const char* pbuf = lds + POSOFF + cb * 256;

        f32x4 sacc[4] = {};
#pragma unroll
        for (int ks = 0; ks < 2; ++ks) {
            const bf16x8 qq = qf[ks];
#pragma unroll
            for (int j = 0; j < 4; ++j) {
                const int krow = j * 16 + (l & 15);
                const bf16x8 kf = *(const bf16x8*)(kbuf + krow * 128 +
                                                   ((((l >> 4) + 4 * ks) ^ (krow & 7)) << 4));
                sacc[j] = __builtin_amdgcn_mfma_f32_16x16x32_bf16(kf, qq, sacc[j], 0, 0, 0);
            }
        }

        int4 pk4[4];
#pragma unroll
        for (int j = 0; j < 4; ++j)
            pk4[j] = *(const int4*)(pbuf + (l >> 4) * 16 + j * 64);

        float sv[16];
#pragma unroll
        for (int j = 0; j < 4; ++j) {
            const int pkk[4] = {pk4[j].x, pk4[j].y, pk4[j].z, pk4[j].w};
#pragma unroll
            for (int r = 0; r < 4; ++r) {
                const int dd = pq ^ pkk[r];
                const float bs = ((dd & 0xFF00) == 0)
                                     ? (((dd & 0xFF) == 0) ? t3 : t1)
                                     : (((dd & 0xFF) == 0) ? t2 : t0);
                sv[j * 4 + r] = sacc[j][r] + bs;
            }
        }
        float pm = sv[0];
#pragma unroll
        for (int i = 1; i < 16; ++i) pm = fmaxf(pm, sv[i]);
        pm = fmaxf(pm, __shfl_xor(pm, 16));
        pm = fmaxf(pm, __shfl_xor(pm, 32));
        const float mnew = fmaxf(m_run, pm);
        float psum = 0.0f;
#pragma unroll
        for (int i = 0; i < 16; ++i) {
            sv[i] = __expf(sv[i] - mnew);
            psum += sv[i];
        }
        psum += __shfl_xor(psum, 16);
        psum += __shfl_xor(psum, 32);
        const float alpha = __expf(m_run - mnew);
        l_run = l_run * alpha + psum;
        m_run = mnew;

#pragma unroll
        for (int r = 0; r < 4; ++r) {
            const float ar = __shfl(alpha, (l >> 4) * 4 + r);
#pragma unroll
            for (int i = 0; i < 4; ++i) pv[i][r] *= ar;
        }

#pragma unroll
        for (int j = 0; j < 4; ++j)
#pragma unroll
            for (int p2 = 0; p2 < 2; ++p2) {
                const uint u = bfr(sv[j * 4 + 2 * p2]) | (bfr(sv[j * 4 + 2 * p2 + 1]) << 16);
                const int adr = pwbase + (((l >> 4) * 8 + 4 * p2 + 32 * j) ^ pswz);
                *(uint*)(lds + adr) = u;
            }

#pragma unroll
        for (int ks = 0; ks < 2; ++ks) {
            const bf16x8 pf = *(const bf16x8*)(lds + pwbase +
                                               ((((l >> 4) + 4 * ks) << 4) ^ pswz));
#pragma unroll
            for (int i = 0; i < 4; ++i) {
                const int vrow = i * 16 + (l & 15);
                const bf16x8 vf = *(const bf16x8*)(vbuf + vrow * 128 +
                                                   ((((l >> 4) + 4 * ks) ^ (vrow & 7)) << 4));
                pv[i] = __builtin_amdgcn_mfma_f32_16x16x32_bf16(pf, vf, pv[i], 0, 0, 0);
            }
        }
        __syncthreads();
    }

    const float rinv = 1.0f / l_run;
#pragma unroll
    for (int r = 0; r < 4; ++r) {
        const float inv = __shfl(rinv, (l >> 4) * 4 + r);
        const int mrow = b * SEQ + q0g + w * 16 + (l >> 4) * 4 + r;
        const size_t base = (size_t)mrow * 768 + h * 64 + prow;
#pragma unroll
        for (int i = 0; i < 4; ++i) {
            const float o = pv[i][r] * inv;
            const uint hu = bfr(o);
            const float hf = __uint_as_float(hu << 16);
            const uint lu = bfr(o - hf);
            aoh[base + 16 * i] = (ushort)hu;
            aol[base + 16 * i] = (ushort)lu;
        }
    }
}

// ---------------------------------------------------------------------------
extern "C" void kernel_launch(void* const* d_in, const int* in_sizes, int n_in,
                              void* d_out, int out_size, void* d_ws, size_t ws_size,
                              hipStream_t stream)
{
    const float* hs      = (const float*)d_in[0];
    const int*   pos_row = (const int*)d_in[1];
    const int*   pos_col = (const int*)d_in[2];
    const float* q_w     = (const float*)d_in[3];
    const float* q_b     = (const float*)d_in[4];
    const float* k_w     = (const float*)d_in[5];
    const float* k_b     = (const float*)d_in[6];
    const float* v_w     = (const float*)d_in[7];
    const float* v_b     = (const float*)d_in[8];
    const float* o_w     = (const float*)d_in[9];
    const float* o_b     = (const float*)d_in[10];
    const float* rel_tab = (const float*)d_in[11];

    char* ws = (char*)d_ws;
    const size_t HS_N = (size_t)MTOT * EMB;
    const size_t W_N  = (size_t)EMB * EMB;
    ushort* hsh = (ushort*)ws;  ws += HS_N * 2;
    ushort* hsl = (ushort*)ws;  ws += HS_N * 2;
    ushort* wch = (ushort*)ws;  ws += 3 * W_N * 2;
    ushort* wcl = (ushort*)ws;  ws += 3 * W_N * 2;
    ushort* woh = (ushort*)ws;  ws += W_N * 2;
    ushort* wol = (ushort*)ws;  ws += W_N * 2;
    ushort* aoh = (ushort*)ws;  ws += HS_N * 2;
    ushort* aol = (ushort*)ws;  ws += HS_N * 2;
    ushort* q16 = (ushort*)ws;  ws += HS_N * 2;
    ushort* k16 = (ushort*)ws;  ws += HS_N * 2;
    ushort* vT16 = (ushort*)ws; ws += HS_N * 2;

    split_all<<<3072 + 4 * 576, 256, 0, stream>>>(
        hs, q_w, k_w, v_w, o_w, hsh, hsl, wch, wcl, woh, wol);

    gemm_qkv<<<dim3(MTOT / 128, 2304 / 128), 256, 0, stream>>>(
        hsh, hsl, wch, wcl, q_b, k_b, v_b, q16, k16, vT16);

    attn_mfma<<<dim3(SEQ / 64, BATCH * NHEADS), 256, 0, stream>>>(
        q16, k16, vT16, pos_row, pos_col, rel_tab, aoh, aol);

    gemm_oproj<<<dim3(MTOT / 64, EMB / 128), 512, 0, stream>>>(
        aoh, aol, woh, wol, o_b, (float*)d_out);
}

// Round 7
// 207.312 us; speedup vs baseline: 1.1977x; 1.1977x over previous
//
#include <hip/hip_runtime.h>

#define NHEADS 12
#define HDIM   64
#define EMB    768
#define SEQ    1024
#define BATCH  4
#define MTOT   (BATCH * SEQ)

typedef __bf16 bf16x8 __attribute__((ext_vector_type(8)));
typedef float  f32x4  __attribute__((ext_vector_type(4)));

#define GLB(p) ((const __attribute__((address_space(1))) uint32_t*)(p))
#define LDS(p) ((__attribute__((address_space(3))) uint32_t*)(p))
#define VMCNT(n) asm volatile("s_waitcnt vmcnt(" #n ")" ::: "memory")
#define LGKM0()  asm volatile("s_waitcnt lgkmcnt(0)" ::: "memory")

__device__ __forceinline__ uint bfr(float f) {  // f32 -> bf16 bits, RNE
    uint u = __float_as_uint(f);
    return (u + 0x7fffu + ((u >> 16) & 1u)) >> 16;
}

// ---------------------------------------------------------------------------
// One launch: split hs + 4 weights to bf16 hi/lo, and pack pos_row/col.
// blocks: [0,3072) hs | [3072,5376) weights | [5376,5392) pos pack
// ---------------------------------------------------------------------------
__global__ __launch_bounds__(256) void split_all(
    const float* __restrict__ hs,
    const float* __restrict__ w0, const float* __restrict__ w1,
    const float* __restrict__ w2, const float* __restrict__ w3,
    const int* __restrict__ pos_row, const int* __restrict__ pos_col,
    ushort* __restrict__ hsh, ushort* __restrict__ hsl,
    ushort* __restrict__ wch, ushort* __restrict__ wcl,
    ushort* __restrict__ woh, ushort* __restrict__ wol,
    int* __restrict__ pos_pk)
{
    const int bx = blockIdx.x;
    if (bx >= 5376) {  // pos packing: 4096 ints
        int i = (bx - 5376) * 256 + threadIdx.x;
        pos_pk[i] = (pos_row[i] << 8) | pos_col[i];
        return;
    }
    const float* src;
    ushort *hi, *lo;
    int i;
    if (bx < 3072) {
        src = hs; hi = hsh; lo = hsl;
        i = bx * 256 + threadIdx.x;
    } else {
        const int y = (bx - 3072) / 576;
        const int r = (bx - 3072) - y * 576;
        src = (y == 0) ? w0 : (y == 1) ? w1 : (y == 2) ? w2 : w3;
        hi = (y < 3) ? (wch + (size_t)y * (EMB * EMB)) : woh;
        lo = (y < 3) ? (wcl + (size_t)y * (EMB * EMB)) : wol;
        i = r * 256 + threadIdx.x;
    }
    float4 v = ((const float4*)src)[i];
    float f[4] = {v.x, v.y, v.z, v.w};
    ushort hh[4], ll[4];
#pragma unroll
    for (int j = 0; j < 4; ++j) {
        uint h = bfr(f[j]);
        float hf = __uint_as_float(h << 16);
        ll[j] = (ushort)bfr(f[j] - hf);
        hh[j] = (ushort)h;
    }
    ushort4 hv = {hh[0], hh[1], hh[2], hh[3]};
    ushort4 lv = {ll[0], ll[1], ll[2], ll[3]};
    ((ushort4*)hi)[i] = hv;
    ((ushort4*)lo)[i] = lv;
}

// ---------------------------------------------------------------------------
// QKV GEMM: round-5 structure (128x128 tile, BK=32, 8 waves of 64x32,
// 16x16x32 MFMA, bf16 hi/lo 3-MFMA) + counted-vmcnt 2-barrier schedule:
// stage(t+1) stays in flight across both barriers (never vmcnt(0) mid-loop).
// ---------------------------------------------------------------------------
__global__ __launch_bounds__(512) void gemm_qkv(
    const ushort* __restrict__ Ah, const ushort* __restrict__ Al,
    const ushort* __restrict__ Wh, const ushort* __restrict__ Wl,
    const float* __restrict__ b0, const float* __restrict__ b1,
    const float* __restrict__ b2,
    ushort* __restrict__ q16, ushort* __restrict__ k16,
    ushort* __restrict__ vT16)
{
    constexpr int TS = 32768;  // [Ah 8K][Al 8K][Wh 8K][Wl 8K]
    __shared__ __align__(16) char ldsc[2 * TS];

    const int t  = threadIdx.x;
    const int w  = t >> 6;
    const int l  = t & 63;
    const int m0 = blockIdx.x * 128;
    const int n0 = blockIdx.y * 128;
    const int wm = w >> 2;   // 0..1
    const int wn = w & 3;    // 0..3

    const char* gb[4] = {
        (const char*)Ah + (size_t)m0 * 1536,
        (const char*)Al + (size_t)m0 * 1536,
        (const char*)Wh + (size_t)n0 * 1536,
        (const char*)Wl + (size_t)n0 * 1536};

    int aoff[4], boff[2];
#pragma unroll
    for (int i = 0; i < 4; ++i) {
        int row = wm * 64 + i * 16 + (l & 15);
        aoff[i] = row * 64 + ((((l >> 4) ^ ((row >> 1) & 3))) << 4);
    }
#pragma unroll
    for (int j = 0; j < 2; ++j) {
        int rn = wn * 32 + j * 16 + (l & 15);
        boff[j] = rn * 64 + ((((l >> 4) ^ ((rn >> 1) & 3))) << 4);
    }

    // stage one K-step (4 global_load_lds / thread, coalesced 64B rows)
    auto stage = [&](int ks, int buf) {
        const size_t kb = (size_t)ks * 64;
        char* dst = ldsc + buf * TS;
        const int soff = t * 16;
        const int srow = soff >> 6;
        const int slot = (soff >> 4) & 3;
        const size_t go = (size_t)srow * 1536 +
                          ((slot ^ ((srow >> 1) & 3)) << 4) + kb;
#pragma unroll
        for (int tt = 0; tt < 4; ++tt)
            __builtin_amdgcn_global_load_lds(GLB(gb[tt] + go),
                                             LDS(dst + tt * 8192 + soff), 16, 0, 0);
    };

    f32x4 acc[4][2] = {};

    stage(0, 0);

    for (int ks = 0; ks < 24; ++ks) {
        if (ks + 1 < 24) {
            stage(ks + 1, (ks + 1) & 1);
            VMCNT(4);               // stage(ks) done; stage(ks+1) in flight
        } else {
            VMCNT(0);
        }
        __builtin_amdgcn_s_barrier();   // tile ks ready for all waves

        const char* cur = ldsc + (ks & 1) * TS;
        bf16x8 ah[4], al[4], bh[2], bl[2];
#pragma unroll
        for (int i = 0; i < 4; ++i) {
            ah[i] = *(const bf16x8*)(cur + aoff[i]);
            al[i] = *(const bf16x8*)(cur + 8192 + aoff[i]);
        }
#pragma unroll
        for (int j = 0; j < 2; ++j) {
            bh[j] = *(const bf16x8*)(cur + 16384 + boff[j]);
            bl[j] = *(const bf16x8*)(cur + 24576 + boff[j]);
        }
        LGKM0();                        // own reads drained (data in regs)
        __builtin_amdgcn_sched_barrier(0);
        __builtin_amdgcn_s_barrier();   // all waves done reading buf ks&1

        __builtin_amdgcn_s_setprio(1);
#pragma unroll
        for (int i = 0; i < 4; ++i)
#pragma unroll
            for (int j = 0; j < 2; ++j) {
                acc[i][j] = __builtin_amdgcn_mfma_f32_16x16x32_bf16(ah[i], bh[j], acc[i][j], 0, 0, 0);
                acc[i][j] = __builtin_amdgcn_mfma_f32_16x16x32_bf16(ah[i], bl[j], acc[i][j], 0, 0, 0);
                acc[i][j] = __builtin_amdgcn_mfma_f32_16x16x32_bf16(al[i], bh[j], acc[i][j], 0, 0, 0);
            }
        __builtin_amdgcn_s_setprio(0);
    }

    const int mrow_base = m0 + wm * 64 + ((l >> 4) << 2);
    const int which = (n0 >= 1536) ? 2 : (n0 >= 768 ? 1 : 0);
    const int nin_base = n0 - which * 768 + wn * 32 + (l & 15);

    if (which == 2) {
#pragma unroll
        for (int j = 0; j < 2; ++j) {
            const int n_in = nin_base + j * 16;
            const float bv = b2[n_in];
            const int h = n_in >> 6, d = n_in & 63;
#pragma unroll
            for (int i = 0; i < 4; ++i) {
                const int m = mrow_base + i * 16;
                const int bb = m >> 10, s = m & 1023;
                ushort4 pk = {(ushort)bfr(acc[i][j][0] + bv),
                              (ushort)bfr(acc[i][j][1] + bv),
                              (ushort)bfr(acc[i][j][2] + bv),
                              (ushort)bfr(acc[i][j][3] + bv)};
                *(ushort4*)(vT16 + (size_t)((bb * NHEADS + h) * HDIM + d) * SEQ + s) = pk;
            }
        }
    } else {
        ushort* op = (which == 0) ? q16 : k16;
        const float* bpt = (which == 0) ? b0 : b1;
        const float scale = (which == 0) ? 0.125f : 1.0f;
#pragma unroll
        for (int j = 0; j < 2; ++j) {
            const int n_in = nin_base + j * 16;
            const float bv = bpt[n_in];
            const int h = n_in >> 6, d = n_in & 63;
#pragma unroll
            for (int i = 0; i < 4; ++i)
#pragma unroll
                for (int r = 0; r < 4; ++r) {
                    const int m = mrow_base + i * 16 + r;
                    const int bb = m >> 10, s = m & 1023;
                    op[(size_t)((bb * NHEADS + h) * SEQ + s) * HDIM + d] =
                        (ushort)bfr((acc[i][j][r] + bv) * scale);
                }
        }
    }
}

// ---------------------------------------------------------------------------
// o-projection: BM=64 x 128, 8 waves of 32x32, same counted-vmcnt schedule.
// Waves 0-3 stage 4 loads/thread (A+W), waves 4-7 stage 2 (W only).
// ---------------------------------------------------------------------------
__global__ __launch_bounds__(512) void gemm_oproj(
    const ushort* __restrict__ Ah, const ushort* __restrict__ Al,
    const ushort* __restrict__ Wh, const ushort* __restrict__ Wl,
    const float* __restrict__ b0, float* __restrict__ o0)
{
    constexpr int SA = 4096;
    constexpr int SB = 8192;
    constexpr int TS = 2 * SA + 2 * SB;  // 24576
    __shared__ __align__(16) char ldsc[2 * TS];

    const int t  = threadIdx.x;
    const int w  = t >> 6;
    const int l  = t & 63;
    const int m0 = blockIdx.x * 64;
    const int n0 = blockIdx.y * 128;
    const int wm = w >> 2;
    const int wn = w & 3;

    const char* gb[4] = {
        (const char*)Ah + (size_t)m0 * 1536,
        (const char*)Al + (size_t)m0 * 1536,
        (const char*)Wh + (size_t)n0 * 1536,
        (const char*)Wl + (size_t)n0 * 1536};

    int aoff[2], boff[2];
#pragma unroll
    for (int i = 0; i < 2; ++i) {
        int row = wm * 32 + i * 16 + (l & 15);
        aoff[i] = row * 64 + ((((l >> 4) ^ ((row >> 1) & 3))) << 4);
    }
#pragma unroll
    for (int i = 0; i < 2; ++i) {
        int rn = wn * 32 + i * 16 + (l & 15);
        boff[i] = rn * 64 + ((((l >> 4) ^ ((rn >> 1) & 3))) << 4);
    }

    auto stage = [&](int ks, int buf) {
        const size_t kb = (size_t)ks * 64;
        char* dst = ldsc + buf * TS;
        const int soff = t * 16;
        const int srow = soff >> 6;
        const int slot = (soff >> 4) & 3;
        const size_t go = (size_t)srow * 1536 +
                          ((slot ^ ((srow >> 1) & 3)) << 4) + kb;
        if (soff < SA) {  // waves 0-3 only
            __builtin_amdgcn_global_load_lds(GLB(gb[0] + go), LDS(dst + soff), 16, 0, 0);
            __builtin_amdgcn_global_load_lds(GLB(gb[1] + go), LDS(dst + SA + soff), 16, 0, 0);
        }
        __builtin_amdgcn_global_load_lds(GLB(gb[2] + go), LDS(dst + 2 * SA + soff), 16, 0, 0);
        __builtin_amdgcn_global_load_lds(GLB(gb[3] + go), LDS(dst + 2 * SA + SB + soff), 16, 0, 0);
    };

    f32x4 acc[2][2] = {};

    stage(0, 0);

    for (int ks = 0; ks < 24; ++ks) {
        if (ks + 1 < 24) {
            stage(ks + 1, (ks + 1) & 1);
            if (w < 4) { VMCNT(4); } else { VMCNT(2); }
        } else {
            VMCNT(0);
        }
        __builtin_amdgcn_s_barrier();

        const char* cur = ldsc + (ks & 1) * TS;
        bf16x8 ah[2], al[2], bh[2], bl[2];
#pragma unroll
        for (int i = 0; i < 2; ++i) {
            ah[i] = *(const bf16x8*)(cur + aoff[i]);
            al[i] = *(const bf16x8*)(cur + SA + aoff[i]);
        }
#pragma unroll
        for (int i = 0; i < 2; ++i) {
            bh[i] = *(const bf16x8*)(cur + 2 * SA + boff[i]);
            bl[i] = *(const bf16x8*)(cur + 2 * SA + SB + boff[i]);
        }
        LGKM0();
        __builtin_amdgcn_sched_barrier(0);
        __builtin_amdgcn_s_barrier();

        __builtin_amdgcn_s_setprio(1);
#pragma unroll
        for (int i = 0; i < 2; ++i)
#pragma unroll
            for (int j = 0; j < 2; ++j) {
                acc[i][j] = __builtin_amdgcn_mfma_f32_16x16x32_bf16(ah[i], bh[j], acc[i][j], 0, 0, 0);
                acc[i][j] = __builtin_amdgcn_mfma_f32_16x16x32_bf16(ah[i], bl[j], acc[i][j], 0, 0, 0);
                acc[i][j] = __builtin_amdgcn_mfma_f32_16x16x32_bf16(al[i], bh[j], acc[i][j], 0, 0, 0);
            }
        __builtin_amdgcn_s_setprio(0);
    }

    const int mrow_base = m0 + wm * 32 + ((l >> 4) << 2);
    const int nin_base = n0 + wn * 32 + (l & 15);
#pragma unroll
    for (int j = 0; j < 2; ++j) {
        const int n_in = nin_base + j * 16;
        const float bv = b0[n_in];
#pragma unroll
        for (int i = 0; i < 2; ++i)
#pragma unroll
            for (int r = 0; r < 4; ++r) {
                const int m = mrow_base + i * 16 + r;
                o0[(size_t)m * 768 + n_in] = acc[i][j][r] + bv;
            }
    }
}

// ---------------------------------------------------------------------------
// Flash attention, bf16 MFMA, double-buffered K/V with counted-vmcnt
// 2-barrier schedule. pos tile staged via global_load_lds from packed pos_pk.
// ---------------------------------------------------------------------------
#define QPOFF  0
#define KOFF   8192
#define VOFF   24576
#define POSOFF 40960

__global__ __launch_bounds__(256) void attn_mfma(
    const ushort* __restrict__ q16, const ushort* __restrict__ k16,
    const ushort* __restrict__ vT16, const int* __restrict__ pos_pk,
    const float* __restrict__ rel_table,
    ushort* __restrict__ aoh, ushort* __restrict__ aol)
{
    __shared__ __align__(16) char lds[41472];

    const int t  = threadIdx.x;
    const int w  = t >> 6;
    const int l  = t & 63;
    const int bh = blockIdx.y;
    const int b  = bh / NHEADS;
    const int h  = bh - b * NHEADS;
    const int q0g = blockIdx.x * 64;

    const char* qb  = (const char*)(q16 + (size_t)bh * SEQ * HDIM);
    const char* kb  = (const char*)(k16 + (size_t)bh * SEQ * HDIM);
    const char* vtb = (const char*)(vT16 + (size_t)bh * HDIM * SEQ);

    const float t0 = rel_table[0 * NHEADS + h];
    const float t1 = rel_table[1 * NHEADS + h];
    const float t2 = rel_table[2 * NHEADS + h];
    const float t3 = rel_table[3 * NHEADS + h];

    const int o1 = t * 16, o2 = o1 + 4096;
    const int r1 = o1 >> 7, r2 = o2 >> 7;
    const int kq1 = o1 ^ ((r1 & 7) << 4);
    const int kq2 = o2 ^ ((r2 & 7) << 4);
    const int vs1 = r1 * 2048 + (((((o1 >> 4) & 7) ^ (r1 & 7))) << 4);
    const int vs2 = r2 * 2048 + (((((o2 >> 4) & 7) ^ (r2 & 7))) << 4);

    // per stage: waves 1-3 issue 4 loads, wave 0 issues 5 (pos)
    auto stage_kv = [&](int kt, int buf) {
        const int k0g = kt * 64;
        __builtin_amdgcn_global_load_lds(GLB(kb + (size_t)k0g * 128 + kq1),
                                         LDS(lds + KOFF + buf * 8192 + w * 1024), 16, 0, 0);
        __builtin_amdgcn_global_load_lds(GLB(kb + (size_t)k0g * 128 + kq2),
                                         LDS(lds + KOFF + buf * 8192 + w * 1024 + 4096), 16, 0, 0);
        __builtin_amdgcn_global_load_lds(GLB(vtb + (size_t)k0g * 2 + vs1),
                                         LDS(lds + VOFF + buf * 8192 + w * 1024), 16, 0, 0);
        __builtin_amdgcn_global_load_lds(GLB(vtb + (size_t)k0g * 2 + vs2),
                                         LDS(lds + VOFF + buf * 8192 + w * 1024 + 4096), 16, 0, 0);
        if (w == 0) {
            __builtin_amdgcn_global_load_lds(GLB(pos_pk + b * SEQ + k0g + l),
                                             LDS(lds + POSOFF + buf * 256), 4, 0, 0);
        }
    };

    __builtin_amdgcn_global_load_lds(GLB(qb + (size_t)q0g * 128 + kq1),
                                     LDS(lds + QPOFF + w * 1024), 16, 0, 0);
    __builtin_amdgcn_global_load_lds(GLB(qb + (size_t)q0g * 128 + kq2),
                                     LDS(lds + QPOFF + w * 1024 + 4096), 16, 0, 0);
    stage_kv(0, 0);

    const int qrow_g = q0g + w * 16 + (l & 15);
    const int pq = pos_pk[b * SEQ + qrow_g];

    VMCNT(0);
    __builtin_amdgcn_s_barrier();

    bf16x8 qf[2];
    const int qrl = w * 16 + (l & 15);
#pragma unroll
    for (int ks = 0; ks < 2; ++ks)
        qf[ks] = *(const bf16x8*)(lds + QPOFF + qrl * 128 +
                                  ((((l >> 4) + 4 * ks) ^ (qrl & 7)) << 4));

    f32x4 pv[4] = {};
    float m_run = -1e30f, l_run = 0.0f;

    const int prow = l & 15;
    const int pswz = (prow & 7) << 4;
    const int pwbase = QPOFF + w * 2048 + prow * 128;

    for (int kt = 0; kt < 16; ++kt) {
        const int cb = kt & 1;
        if (kt + 1 < 16) {
            stage_kv(kt + 1, cb ^ 1);
            if (w == 0) { VMCNT(5); } else { VMCNT(4); }
        } else {
            VMCNT(0);
        }
        __builtin_amdgcn_s_barrier();   // tile kt ready

        const char* kbuf = lds + KOFF + cb * 8192;
        const char* vbuf = lds + VOFF + cb * 8192;
        const char* pbuf = lds + POSOFF + cb * 256;

        f32x4 sacc[4] = {};
        __builtin_amdgcn_s_setprio(1);
#pragma unroll
        for (int ks = 0; ks < 2; ++ks) {
            const bf16x8 qq = qf[ks];
#pragma unroll
            for (int j = 0; j < 4; ++j) {
                const int krow = j * 16 + (l & 15);
                const bf16x8 kf = *(const bf16x8*)(kbuf + krow * 128 +
                                                   ((((l >> 4) + 4 * ks) ^ (krow & 7)) << 4));
                sacc[j] = __builtin_amdgcn_mfma_f32_16x16x32_bf16(kf, qq, sacc[j], 0, 0, 0);
            }
        }
        __builtin_amdgcn_s_setprio(0);

        int4 pk4[4];
#pragma unroll
        for (int j = 0; j < 4; ++j)
            pk4[j] = *(const int4*)(pbuf + (l >> 4) * 16 + j * 64);

        float sv[16];
#pragma unroll
        for (int j = 0; j < 4; ++j) {
            const int pkk[4] = {pk4[j].x, pk4[j].y, pk4[j].z, pk4[j].w};
#pragma unroll
            for (int r = 0; r < 4; ++r) {
                const int dd = pq ^ pkk[r];
                const float bs = ((dd & 0xFF00) == 0)
                                     ? (((dd & 0xFF) == 0) ? t3 : t1)
                                     : (((dd & 0xFF) == 0) ? t2 : t0);
                sv[j * 4 + r] = sacc[j][r] + bs;
            }
        }
        float pm = sv[0];
#pragma unroll
        for (int i = 1; i < 16; ++i) pm = fmaxf(pm, sv[i]);
        pm = fmaxf(pm, __shfl_xor(pm, 16));
        pm = fmaxf(pm, __shfl_xor(pm, 32));
        const float mnew = fmaxf(m_run, pm);
        float psum = 0.0f;
#pragma unroll
        for (int i = 0; i < 16; ++i) {
            sv[i] = __expf(sv[i] - mnew);
            psum += sv[i];
        }
        psum += __shfl_xor(psum, 16);
        psum += __shfl_xor(psum, 32);
        const float alpha = __expf(m_run - mnew);
        l_run = l_run * alpha + psum;
        m_run = mnew;

#pragma unroll
        for (int r = 0; r < 4; ++r) {
            const float ar = __shfl(alpha, (l >> 4) * 4 + r);
#pragma unroll
            for (int i = 0; i < 4; ++i) pv[i][r] *= ar;
        }

#pragma unroll
        for (int j = 0; j < 4; ++j)
#pragma unroll
            for (int p2 = 0; p2 < 2; ++p2) {
                const uint u = bfr(sv[j * 4 + 2 * p2]) | (bfr(sv[j * 4 + 2 * p2 + 1]) << 16);
                const int adr = pwbase + (((l >> 4) * 8 + 4 * p2 + 32 * j) ^ pswz);
                *(uint*)(lds + adr) = u;
            }

        __builtin_amdgcn_s_setprio(1);
#pragma unroll
        for (int ks = 0; ks < 2; ++ks) {
            const bf16x8 pf = *(const bf16x8*)(lds + pwbase +
                                               ((((l >> 4) + 4 * ks) << 4) ^ pswz));
#pragma unroll
            for (int i = 0; i < 4; ++i) {
                const int vrow = i * 16 + (l & 15);
                const bf16x8 vf = *(const bf16x8*)(vbuf + vrow * 128 +
                                                   ((((l >> 4) + 4 * ks) ^ (vrow & 7)) << 4));
                pv[i] = __builtin_amdgcn_mfma_f32_16x16x32_bf16(pf, vf, pv[i], 0, 0, 0);
            }
        }
        __builtin_amdgcn_s_setprio(0);

        LGKM0();                        // all my LDS reads of tile kt done
        __builtin_amdgcn_sched_barrier(0);
        __builtin_amdgcn_s_barrier();   // all waves done with buf kt
    }

    const float rinv = 1.0f / l_run;
#pragma unroll
    for (int r = 0; r < 4; ++r) {
        const float inv = __shfl(rinv, (l >> 4) * 4 + r);
        const int mrow = b * SEQ + q0g + w * 16 + (l >> 4) * 4 + r;
        const size_t base = (size_t)mrow * 768 + h * 64 + prow;
#pragma unroll
        for (int i = 0; i < 4; ++i) {
            const float o = pv[i][r] * inv;
            const uint hu = bfr(o);
            const float hf = __uint_as_float(hu << 16);
            const uint lu = bfr(o - hf);
            aoh[base + 16 * i] = (ushort)hu;
            aol[base + 16 * i] = (ushort)lu;
        }
    }
}

// ---------------------------------------------------------------------------
extern "C" void kernel_launch(void* const* d_in, const int* in_sizes, int n_in,
                              void* d_out, int out_size, void* d_ws, size_t ws_size,
                              hipStream_t stream)
{
    const float* hs      = (const float*)d_in[0];
    const int*   pos_row = (const int*)d_in[1];
    const int*   pos_col = (const int*)d_in[2];
    const float* q_w     = (const float*)d_in[3];
    const float* q_b     = (const float*)d_in[4];
    const float* k_w     = (const float*)d_in[5];
    const float* k_b     = (const float*)d_in[6];
    const float* v_w     = (const float*)d_in[7];
    const float* v_b     = (const float*)d_in[8];
    const float* o_w     = (const float*)d_in[9];
    const float* o_b     = (const float*)d_in[10];
    const float* rel_tab = (const float*)d_in[11];

    char* ws = (char*)d_ws;
    const size_t HS_N = (size_t)MTOT * EMB;
    const size_t W_N  = (size_t)EMB * EMB;
    ushort* hsh = (ushort*)ws;  ws += HS_N * 2;
    ushort* hsl = (ushort*)ws;  ws += HS_N * 2;
    ushort* wch = (ushort*)ws;  ws += 3 * W_N * 2;
    ushort* wcl = (ushort*)ws;  ws += 3 * W_N * 2;
    ushort* woh = (ushort*)ws;  ws += W_N * 2;
    ushort* wol = (ushort*)ws;  ws += W_N * 2;
    ushort* aoh = (ushort*)ws;  ws += HS_N * 2;
    ushort* aol = (ushort*)ws;  ws += HS_N * 2;
    ushort* q16 = (ushort*)ws;  ws += HS_N * 2;
    ushort* k16 = (ushort*)ws;  ws += HS_N * 2;
    ushort* vT16 = (ushort*)ws; ws += HS_N * 2;
    int* pos_pk = (int*)ws;     ws += MTOT * 4;

    split_all<<<5392, 256, 0, stream>>>(
        hs, q_w, k_w, v_w, o_w, pos_row, pos_col,
        hsh, hsl, wch, wcl, woh, wol, pos_pk);

    gemm_qkv<<<dim3(MTOT / 128, 2304 / 128), 512, 0, stream>>>(
        hsh, hsl, wch, wcl, q_b, k_b, v_b, q16, k16, vT16);

    attn_mfma<<<dim3(SEQ / 64, BATCH * NHEADS), 256, 0, stream>>>(
        q16, k16, vT16, pos_pk, rel_tab, aoh, aol);

    gemm_oproj<<<dim3(MTOT / 64, EMB / 128), 512, 0, stream>>>(
        aoh, aol, woh, wol, o_b, (float*)d_out);
}